// Round 1
// baseline (857.741 us; speedup 1.0000x reference)
//
#include <hip/hip_runtime.h>
#include <hip/hip_bf16.h>
#include <stdint.h>

#define BATCH 8
#define NQ 4096
#define NK 4096
#define DD 512
#define BM 128
#define BN 128
#define BK 64

typedef short bf16x8 __attribute__((ext_vector_type(8)));
typedef float f32x4  __attribute__((ext_vector_type(4)));
typedef unsigned short u16x8 __attribute__((ext_vector_type(8)));

__device__ __forceinline__ unsigned short f2bf_rne(float f) {
    union { float f; uint32_t u; } v; v.f = f;
    uint32_t u = v.u;
    u += 0x7FFFu + ((u >> 16) & 1u);   // round-to-nearest-even
    return (unsigned short)(u >> 16);
}

// One wave per 512-elem row: fp32 sum-of-squares (exact inputs) + bf16 convert.
__global__ __launch_bounds__(256) void prep_kernel(
    const float* __restrict__ keys, const float* __restrict__ queries,
    unsigned short* __restrict__ kb, unsigned short* __restrict__ qb,
    float* __restrict__ ksq, float* __restrict__ qsq)
{
    const int wave = threadIdx.x >> 6;
    const int lane = threadIdx.x & 63;
    const int rid  = blockIdx.x * 4 + wave;        // 0..65535
    const int ROWS = BATCH * NQ;                   // 32768 rows per tensor
    const float* src; unsigned short* db; float* dn; int row;
    if (rid < ROWS) { src = keys;    db = kb; dn = ksq; row = rid; }
    else            { src = queries; db = qb; dn = qsq; row = rid - ROWS; }

    const float* p = src + (size_t)row * DD + lane * 8;
    float4 v0 = ((const float4*)p)[0];
    float4 v1 = ((const float4*)p)[1];
    float s = v0.x*v0.x + v0.y*v0.y + v0.z*v0.z + v0.w*v0.w
            + v1.x*v1.x + v1.y*v1.y + v1.z*v1.z + v1.w*v1.w;
    #pragma unroll
    for (int m = 32; m >= 1; m >>= 1) s += __shfl_xor(s, m);

    u16x8 o;
    o[0] = f2bf_rne(v0.x); o[1] = f2bf_rne(v0.y);
    o[2] = f2bf_rne(v0.z); o[3] = f2bf_rne(v0.w);
    o[4] = f2bf_rne(v1.x); o[5] = f2bf_rne(v1.y);
    o[6] = f2bf_rne(v1.z); o[7] = f2bf_rne(v1.w);
    *(u16x8*)(db + (size_t)row * DD + lane * 8) = o;
    if (lane == 0) dn[row] = s;
}

// 128x128 tile NT-GEMM (both operands row-major, contiguous d) with fused
// distance epilogue. 4 waves, each computes a 64x64 sub-tile as 4x4 MFMA
// 16x16x32_bf16 tiles. Staging: global_load_lds width=16, XOR-swizzled
// granules so ds_read_b128 is ~conflict-free (2-way max).
__global__ __launch_bounds__(256) void score_kernel(
    const unsigned short* __restrict__ qb, const unsigned short* __restrict__ kb,
    const float* __restrict__ qsq, const float* __restrict__ ksq,
    float* __restrict__ out)
{
    __shared__ unsigned short sA[BM * BK];  // 16 KB
    __shared__ unsigned short sB[BN * BK];  // 16 KB

    const int b    = blockIdx.z;
    const int tm   = blockIdx.y * BM;      // query-row base
    const int tn   = blockIdx.x * BN;      // key-col base
    const int tid  = threadIdx.x;
    const int wave = tid >> 6;
    const int lane = tid & 63;
    const int wm   = wave & 1;
    const int wn   = wave >> 1;

    const unsigned short* Ab = qb + (size_t)b * NQ * DD;
    const unsigned short* Bb = kb + (size_t)b * NK * DD;

    const int r8  = lane >> 3;             // row within 8-row staging group
    const int gsw = (lane & 7) ^ r8;       // swizzled source granule (8 bf16)

    const int frow = lane & 15;            // fragment row/col within 16-tile
    const int fq   = lane >> 4;            // quad index 0..3

    f32x4 acc[4][4] = {};

    for (int kt = 0; kt < DD / BK; ++kt) {
        const int k0 = kt * BK;
        #pragma unroll
        for (int j = 0; j < 4; ++j) {
            const int rloc = wave * 32 + j * 8;   // wave-uniform tile-row base
            const unsigned short* ga = Ab + (size_t)(tm + rloc + r8) * DD + k0 + gsw * 8;
            __builtin_amdgcn_global_load_lds(
                (const __attribute__((address_space(1))) void*)ga,
                (__attribute__((address_space(3))) void*)&sA[rloc * BK],
                16, 0, 0);
            const unsigned short* gb = Bb + (size_t)(tn + rloc + r8) * DD + k0 + gsw * 8;
            __builtin_amdgcn_global_load_lds(
                (const __attribute__((address_space(1))) void*)gb,
                (__attribute__((address_space(3))) void*)&sB[rloc * BK],
                16, 0, 0);
        }
        __syncthreads();

        #pragma unroll
        for (int ks = 0; ks < BK / 32; ++ks) {
            bf16x8 af[4], bf[4];
            #pragma unroll
            for (int t = 0; t < 4; ++t) {
                const int ra = wm * 64 + t * 16 + frow;
                const int ga_ = (ks * 4 + fq) ^ (ra & 7);
                af[t] = *(const bf16x8*)&sA[ra * BK + ga_ * 8];
                const int rb = wn * 64 + t * 16 + frow;
                const int gb_ = (ks * 4 + fq) ^ (rb & 7);
                bf[t] = *(const bf16x8*)&sB[rb * BK + gb_ * 8];
            }
            #pragma unroll
            for (int mt = 0; mt < 4; ++mt) {
                #pragma unroll
                for (int nt = 0; nt < 4; ++nt) {
                    acc[mt][nt] = __builtin_amdgcn_mfma_f32_16x16x32_bf16(
                        af[mt], bf[nt], acc[mt][nt], 0, 0, 0);
                }
            }
        }
        __syncthreads();
    }

    // Epilogue: d2 = qsq + ksq - 2*qk; out = 1/(1+sqrt(max(d2, EPS)))
    // C/D layout: col = lane&15, row = (lane>>4)*4 + reg  [m89/m91 verified]
    const float* qn = qsq + b * NQ;
    const float* kn = ksq + b * NK;
    float* ob = out + (size_t)b * NQ * NK;
    #pragma unroll
    for (int mt = 0; mt < 4; ++mt) {
        const int row0 = tm + wm * 64 + mt * 16 + fq * 4;
        float qv[4];
        #pragma unroll
        for (int r = 0; r < 4; ++r) qv[r] = qn[row0 + r];
        #pragma unroll
        for (int nt = 0; nt < 4; ++nt) {
            const int col = tn + wn * 64 + nt * 16 + frow;
            const float kv = kn[col];
            #pragma unroll
            for (int r = 0; r < 4; ++r) {
                float d2 = qv[r] + kv - 2.0f * acc[mt][nt][r];
                d2 = fmaxf(d2, 1e-12f);
                const float dist = sqrtf(d2);
                ob[(size_t)(row0 + r) * NK + col] = 1.0f / (1.0f + dist);
            }
        }
    }
}

extern "C" void kernel_launch(void* const* d_in, const int* in_sizes, int n_in,
                              void* d_out, int out_size, void* d_ws, size_t ws_size,
                              hipStream_t stream) {
    (void)in_sizes; (void)n_in; (void)out_size; (void)ws_size;
    const float* keys    = (const float*)d_in[0];   // (8,4096,512)
    const float* queries = (const float*)d_in[1];   // (8,4096,512)
    float* out = (float*)d_out;                     // (8,4096,4096)

    char* ws = (char*)d_ws;
    unsigned short* qb  = (unsigned short*)ws;                              // 32 MB bf16 queries
    unsigned short* kb  = (unsigned short*)(ws + ((size_t)32 << 20));       // 32 MB bf16 keys
    float*          qsq = (float*)(ws + ((size_t)64 << 20));                // 128 KB
    float*          ksq = (float*)(ws + ((size_t)64 << 20) + (128 << 10));  // 128 KB

    prep_kernel<<<dim3((2 * BATCH * NQ) / 4 / 1), 256, 0, stream>>>(
        keys, queries, kb, qb, ksq, qsq);  // 65536 rows / 4 waves = 16384 blocks

    score_kernel<<<dim3(NK / BN, NQ / BM, BATCH), 256, 0, stream>>>(
        qb, kb, qsq, ksq, out);
}